// Round 4
// baseline (718.122 us; speedup 1.0000x reference)
//
#include <hip/hip_runtime.h>
#include <math.h>

// UpTransition: up-GEMM -> sparse conv(32) -> BN+ELU -> cat(skip max) ->
// 2x [sparse conv(64) -> BN+ELU] -> ELU(h + xcat)
//
// Sparse convs: per-k dense pair lists -> partial rows in compacted C buffer
// (no atomics, coalesced), then gather-reduce through pos[k][out] table.
// GEMM inner loop: x row via wave-uniform scalar loads (SGPR), weights cached
// in 64 VGPRs per wave -> v_fmac v, s, v; 4-way split accumulator breaks the
// 64-deep dependent FMA chain (16-deep per partial -> 1-2 waves cover latency).

__device__ __forceinline__ float elu(float v) { return v > 0.f ? v : expm1f(v); }

__device__ __forceinline__ float4 f4add(float4 a, float4 b) {
  return make_float4(a.x + b.x, a.y + b.y, a.z + b.z, a.w + b.w);
}

// dot(x[0..63], w[0..63]) with 4 partial accumulators
__device__ __forceinline__ float dot64(const float* __restrict__ xr, const float* wreg) {
  float a0 = 0.f, a1 = 0.f, a2 = 0.f, a3 = 0.f;
#pragma unroll
  for (int ci = 0; ci < 64; ci += 4) {
    a0 = fmaf(xr[ci + 0], wreg[ci + 0], a0);
    a1 = fmaf(xr[ci + 1], wreg[ci + 1], a1);
    a2 = fmaf(xr[ci + 2], wreg[ci + 2], a2);
    a3 = fmaf(xr[ci + 3], wreg[ci + 3], a3);
  }
  return (a0 + a1) + (a2 + a3);
}

// ---------------- init: pos = -1, stats = 0, zero pad rows ----------------
__global__ void __launch_bounds__(256) k_init(int* __restrict__ pos, float* __restrict__ stats,
                                              float* __restrict__ upz, float* __restrict__ xcz,
                                              int n_pos) {
  int i = blockIdx.x * blockDim.x + threadIdx.x;
  for (int j = i; j < n_pos; j += gridDim.x * blockDim.x) pos[j] = -1;
  if (i < 384) stats[i] = 0.f;
  if (i < 64) { upz[i] = 0.f; xcz[i] = 0.f; }
}

// ---------------- meta: per-k counts (binary search on NF padding) + bases --
__global__ void k_meta(const int* __restrict__ in_idx, int mmax, int NF,
                       int* __restrict__ cnt, int* __restrict__ base) {
  __shared__ int sc[27];
  int k = threadIdx.x;
  if (k < 27) {
    int lo = 0, hi = mmax;
    while (lo < hi) {
      int mid = (lo + hi) >> 1;
      if (in_idx[(size_t)k * mmax + mid] >= NF) hi = mid; else lo = mid + 1;
    }
    sc[k] = lo;
    cnt[k] = lo;
  }
  __syncthreads();
  if (threadIdx.x == 0) {
    int acc = 0;
    for (int j = 0; j < 27; ++j) { base[j] = acc; acc += (sc[j] + 127) & ~127; }
    base[27] = acc;
  }
}

// ---------------- scatter: pos[k][out] = base[k] + m ----------------
__global__ void __launch_bounds__(256) k_scatter(const int* __restrict__ out_idx, int mmax, int NF,
                                                 const int* __restrict__ cnt, const int* __restrict__ base,
                                                 int* __restrict__ pos) {
  int k = blockIdx.y;
  int m = blockIdx.x * blockDim.x + threadIdx.x;
  if (m >= cnt[k]) return;
  pos[(size_t)k * NF + out_idx[(size_t)k * mmax + m]] = base[k] + m;
}

// ---------------- up: up[4n+j] = x[n] @ w_up[j] ----------------
template <int RU>
__global__ void __launch_bounds__(256) k_up(const float* __restrict__ x, const float* __restrict__ w_up,
                                            float* __restrict__ up, int NC) {
  const int lane = threadIdx.x & 63;
  const int j = threadIdx.x >> 6;  // wave = which of the 4 transpose-conv taps
  float wreg[64];
#pragma unroll
  for (int ci = 0; ci < 64; ++ci) wreg[ci] = w_up[(size_t)(j * 64 + ci) * 64 + lane];
  const int n0 = blockIdx.x * RU;
#pragma unroll
  for (int r = 0; r < RU; ++r) {
    int n = n0 + r;
    if (n >= NC) break;
    const float* xr = x + (size_t)n * 64;  // wave-uniform -> scalar loads
    up[(size_t)(n * 4 + j) * 64 + lane] = dot64(xr, wreg);
  }
}

// ---------------- pair-list GEMM: C[base[k]+m] = x[in_idx[k][m]] @ w[k] ----
template <int COUT, int RP>
__global__ void __launch_bounds__(256) k_gemm(const float* __restrict__ x,   // (NF+1) x 64, row NF zero
                                              const float* __restrict__ w,   // [27][64][COUT]
                                              const int* __restrict__ in_idx, int mmax, int NF,
                                              const int* __restrict__ cnt, const int* __restrict__ base,
                                              float* __restrict__ Cbuf) {
  const int k = blockIdx.y;
  const int lane = threadIdx.x & 63;
  const int wv = threadIdx.x >> 6;
  const int ck = cnt[k];
  const int m0 = (blockIdx.x * 4 + wv) * RP;
  if (m0 >= ck) return;
  const int c = lane & (COUT - 1);
  float wreg[64];
#pragma unroll
  for (int ci = 0; ci < 64; ++ci) wreg[ci] = w[(size_t)(k * 64 + ci) * COUT + c];
  const int bk = base[k];
  const int* iik = in_idx + (size_t)k * mmax;
  float acc[RP];
#pragma unroll
  for (int r = 0; r < RP; ++r) {
    int m = m0 + r;
    int in = (m < mmax) ? iik[m] : NF;        // pads gather the zero row
    in = __builtin_amdgcn_readfirstlane(in);  // force SGPR / uniform
    acc[r] = dot64(x + (size_t)in * 64, wreg);  // v_fmac v, s, v
  }
  if (lane < COUT) {
#pragma unroll
    for (int r = 0; r < RP; ++r) Cbuf[(size_t)(bk + m0 + r) * COUT + lane] = acc[r];
  }
}

// ---------------- reduce partials + BN stats ----------------
template <int COUT>
__global__ void __launch_bounds__(256) k_red(const float* __restrict__ Cbuf, const int* __restrict__ pos,
                                             float* __restrict__ y, float* __restrict__ s1,
                                             float* __restrict__ s2, int NF) {
  constexpr int C4 = COUT / 4;
  const int c4 = threadIdx.x & (C4 - 1);
  const int rl = threadIdx.x / C4;
  const int rpb = 256 / C4;
  float4 p1 = make_float4(0, 0, 0, 0), p2 = make_float4(0, 0, 0, 0);
  for (int o = blockIdx.x * rpb + rl; o < NF; o += gridDim.x * rpb) {
    float4 acc = make_float4(0, 0, 0, 0);
#pragma unroll
    for (int k = 0; k < 27; ++k) {
      int p = pos[(size_t)k * NF + o];
      if (p >= 0) {
        float4 v = *(const float4*)(Cbuf + (size_t)p * COUT + c4 * 4);
        acc = f4add(acc, v);
      }
    }
    *(float4*)(y + (size_t)o * COUT + c4 * 4) = acc;
    p1 = f4add(p1, acc);
    p2 = f4add(p2, make_float4(acc.x * acc.x, acc.y * acc.y, acc.z * acc.z, acc.w * acc.w));
  }
  __shared__ float4 sh[256];
  sh[threadIdx.x] = p1;
  __syncthreads();
  if (rl == 0) {
    float4 t = make_float4(0, 0, 0, 0);
    for (int r = 0; r < rpb; ++r) t = f4add(t, sh[r * C4 + c4]);
    atomicAdd(s1 + c4 * 4 + 0, t.x); atomicAdd(s1 + c4 * 4 + 1, t.y);
    atomicAdd(s1 + c4 * 4 + 2, t.z); atomicAdd(s1 + c4 * 4 + 3, t.w);
  }
  __syncthreads();
  sh[threadIdx.x] = p2;
  __syncthreads();
  if (rl == 0) {
    float4 t = make_float4(0, 0, 0, 0);
    for (int r = 0; r < rpb; ++r) t = f4add(t, sh[r * C4 + c4]);
    atomicAdd(s2 + c4 * 4 + 0, t.x); atomicAdd(s2 + c4 * 4 + 1, t.y);
    atomicAdd(s2 + c4 * 4 + 2, t.z); atomicAdd(s2 + c4 * 4 + 3, t.w);
  }
}

// ---------------- xcat = [ELU(BN(y1)), max_t(skip)] ----------------
__global__ void __launch_bounds__(256) k_xcat(const float* __restrict__ y1, const float* __restrict__ skip,
                                              const float* __restrict__ gamma, const float* __restrict__ beta,
                                              const float* __restrict__ s1, const float* __restrict__ s2,
                                              float* __restrict__ xcat, int NF) {
  int t = blockIdx.x * blockDim.x + threadIdx.x;
  if (t >= NF * 32) return;
  int c = t & 31, o = t >> 5;
  float invn = 1.f / (float)NF;
  float m = s1[c] * invn;
  float var = s2[c] * invn - m * m;
  float sc = rsqrtf(var + 1e-5f) * gamma[c];
  float v = (y1[(size_t)o * 32 + c] - m) * sc + beta[c];
  xcat[(size_t)o * 64 + c] = elu(v);
  float a = skip[((size_t)o * 2) * 32 + c];
  float b = skip[((size_t)o * 2 + 1) * 32 + c];
  xcat[(size_t)o * 64 + 32 + c] = fmaxf(a, b);
}

// ---------------- h = ELU(BN(y)) ----------------
__global__ void __launch_bounds__(256) k_norm(const float* __restrict__ y, const float* __restrict__ gamma,
                                              const float* __restrict__ beta, const float* __restrict__ s1,
                                              const float* __restrict__ s2, float* __restrict__ h, int NF) {
  int t = blockIdx.x * blockDim.x + threadIdx.x;
  if (t >= NF * 64) return;
  int c = t & 63;
  float invn = 1.f / (float)NF;
  float m = s1[c] * invn;
  float var = s2[c] * invn - m * m;
  float sc = rsqrtf(var + 1e-5f) * gamma[c];
  h[t] = elu((y[t] - m) * sc + beta[c]);
}

// ---------------- out = ELU(ELU(BN(y3)) + xcat) ----------------
__global__ void __launch_bounds__(256) k_final(const float* __restrict__ y, const float* __restrict__ gamma,
                                               const float* __restrict__ beta, const float* __restrict__ s1,
                                               const float* __restrict__ s2, const float* __restrict__ xcat,
                                               float* __restrict__ out, int NF) {
  int t = blockIdx.x * blockDim.x + threadIdx.x;
  if (t >= NF * 64) return;
  int c = t & 63;
  float invn = 1.f / (float)NF;
  float m = s1[c] * invn;
  float var = s2[c] * invn - m * m;
  float sc = rsqrtf(var + 1e-5f) * gamma[c];
  float v = elu((y[t] - m) * sc + beta[c]);
  out[t] = elu(v + xcat[t]);
}

extern "C" void kernel_launch(void* const* d_in, const int* in_sizes, int n_in,
                              void* d_out, int out_size, void* d_ws, size_t ws_size,
                              hipStream_t stream) {
  const float* x_feats  = (const float*)d_in[0];
  const float* skip     = (const float*)d_in[1];
  const float* w_up     = (const float*)d_in[2];
  const float* w_upconv = (const float*)d_in[3];
  const float* bn1_g    = (const float*)d_in[4];
  const float* bn1_b    = (const float*)d_in[5];
  const float* convs_w  = (const float*)d_in[6];
  const float* convs_g  = (const float*)d_in[7];
  const float* convs_b  = (const float*)d_in[8];
  const int*   in_idx   = (const int*)d_in[9];
  const int*   out_idx  = (const int*)d_in[10];

  const int NC = in_sizes[0] / 64;
  const int NF = 4 * NC;
  const int mmax = in_sizes[9] / 27;

  char* ws = (char*)d_ws;
  size_t off = 0;
  auto alloc = [&](size_t bytes) -> void* {
    void* p = ws + off;
    off += (bytes + 255) & ~(size_t)255;
    return p;
  };
  int*   pos   = (int*)alloc((size_t)27 * NF * 4);
  int*   cnt   = (int*)alloc(32 * 4);
  int*   basep = (int*)alloc(32 * 4);
  float* stats = (float*)alloc(384 * 4);  // 3 stages x (sum, sumsq) x 64
  float* up    = (float*)alloc(((size_t)NF + 1) * 64 * 4);
  float* xcat  = (float*)alloc(((size_t)NF + 1) * 64 * 4);
  float* y     = (float*)alloc((size_t)NF * 64 * 4);  // reused y1/y2/y3
  float* Cb    = (float*)(ws + off);                  // remainder: partial rows
  float* h     = up;  // up is dead after the first k_gemm; pad row stays zero

  k_init<<<1024, 256, 0, stream>>>(pos, stats, up + (size_t)NF * 64,
                                   xcat + (size_t)NF * 64, 27 * NF);
  k_meta<<<1, 64, 0, stream>>>(in_idx, mmax, NF, cnt, basep);
  dim3 gs((mmax + 255) / 256, 27);
  k_scatter<<<gs, 256, 0, stream>>>(out_idx, mmax, NF, cnt, basep, pos);
  k_up<16><<<(NC + 15) / 16, 256, 0, stream>>>(x_feats, w_up, up, NC);

  dim3 gg((mmax + 63) / 64, 27);  // 4 waves x 16 pairs per block; early-exit past cnt[k]
  // upconv (COUT=32) -> BN1 stats
  k_gemm<32, 16><<<gg, 256, 0, stream>>>(up, w_upconv, in_idx, mmax, NF, cnt, basep, Cb);
  k_red<32><<<320, 256, 0, stream>>>(Cb, pos, y, stats + 0, stats + 64, NF);
  k_xcat<<<(NF * 32 + 255) / 256, 256, 0, stream>>>(y, skip, bn1_g, bn1_b,
                                                    stats + 0, stats + 64, xcat, NF);
  // conv1
  k_gemm<64, 16><<<gg, 256, 0, stream>>>(xcat, convs_w, in_idx, mmax, NF, cnt, basep, Cb);
  k_red<64><<<640, 256, 0, stream>>>(Cb, pos, y, stats + 128, stats + 192, NF);
  k_norm<<<(NF * 64 + 255) / 256, 256, 0, stream>>>(y, convs_g, convs_b,
                                                    stats + 128, stats + 192, h, NF);
  // conv2
  k_gemm<64, 16><<<gg, 256, 0, stream>>>(h, convs_w + 27 * 64 * 64, in_idx, mmax, NF, cnt, basep, Cb);
  k_red<64><<<640, 256, 0, stream>>>(Cb, pos, y, stats + 256, stats + 320, NF);
  k_final<<<(NF * 64 + 255) / 256, 256, 0, stream>>>(y, convs_g + 64, convs_b + 64,
                                                     stats + 256, stats + 320, xcat,
                                                     (float*)d_out, NF);
}

// Round 6
// 459.647 us; speedup vs baseline: 1.5623x; 1.5623x over previous
//
#include <hip/hip_runtime.h>
#include <math.h>

// UpTransition: up-GEMM -> sparse conv(32) -> BN+ELU -> cat(skip max) ->
// 2x [sparse conv(64) -> BN+ELU] -> ELU(h + xcat)
//
// R4 post-mortem: SGPR-row gemm was latency-bound (148us each; serial
// s_load row -> 64 FMA chains, occ 26%). Replaced with LDS-tiled GEMM:
// 64 gathered rows staged transposed in LDS (pad 68: b128-aligned,
// conflict-free reads), weight panel in LDS, 4x(COUT/16) micro-tile per
// thread, 16 independent FMA chains -> throughput-bound.

__device__ __forceinline__ float elu(float v) { return v > 0.f ? v : expm1f(v); }

__device__ __forceinline__ float4 f4add(float4 a, float4 b) {
  return make_float4(a.x + b.x, a.y + b.y, a.z + b.z, a.w + b.w);
}

// ---------------- init: pos = -1, stats = 0, zero pad rows ----------------
__global__ void __launch_bounds__(256) k_init(int* __restrict__ pos, float* __restrict__ stats,
                                              float* __restrict__ upz, float* __restrict__ xcz,
                                              int n_pos) {
  int i = blockIdx.x * blockDim.x + threadIdx.x;
  for (int j = i; j < n_pos; j += gridDim.x * blockDim.x) pos[j] = -1;
  if (i < 384) stats[i] = 0.f;
  if (i < 64) { upz[i] = 0.f; xcz[i] = 0.f; }
}

// ---------------- meta: per-k counts (binary search on NF padding) + bases --
__global__ void k_meta(const int* __restrict__ in_idx, int mmax, int NF,
                       int* __restrict__ cnt, int* __restrict__ base) {
  __shared__ int sc[27];
  int k = threadIdx.x;
  if (k < 27) {
    int lo = 0, hi = mmax;
    while (lo < hi) {
      int mid = (lo + hi) >> 1;
      if (in_idx[(size_t)k * mmax + mid] >= NF) hi = mid; else lo = mid + 1;
    }
    sc[k] = lo;
    cnt[k] = lo;
  }
  __syncthreads();
  if (threadIdx.x == 0) {
    int acc = 0;
    for (int j = 0; j < 27; ++j) { base[j] = acc; acc += (sc[j] + 127) & ~127; }
    base[27] = acc;
  }
}

// ---------------- scatter: pos[k][out] = base[k] + m ----------------
__global__ void __launch_bounds__(256) k_scatter(const int* __restrict__ out_idx, int mmax, int NF,
                                                 const int* __restrict__ cnt, const int* __restrict__ base,
                                                 int* __restrict__ pos) {
  int k = blockIdx.y;
  int m = blockIdx.x * blockDim.x + threadIdx.x;
  if (m >= cnt[k]) return;
  pos[(size_t)k * NF + out_idx[(size_t)k * mmax + m]] = base[k] + m;
}

// ---------------- up: up[4n+j] = x[n] @ w_up[j] ----------------
template <int RU>
__global__ void __launch_bounds__(256) k_up(const float* __restrict__ x, const float* __restrict__ w_up,
                                            float* __restrict__ up, int NC) {
  const int lane = threadIdx.x & 63;
  const int j = threadIdx.x >> 6;  // wave = which of the 4 transpose-conv taps
  float wreg[64];
#pragma unroll
  for (int ci = 0; ci < 64; ++ci) wreg[ci] = w_up[(size_t)(j * 64 + ci) * 64 + lane];
  const int n0 = blockIdx.x * RU;
#pragma unroll
  for (int r = 0; r < RU; ++r) {
    int n = n0 + r;
    if (n >= NC) break;
    const float* xr = x + (size_t)n * 64;  // wave-uniform -> scalar loads
    float a0 = 0.f, a1 = 0.f, a2 = 0.f, a3 = 0.f;
#pragma unroll
    for (int ci = 0; ci < 64; ci += 4) {
      a0 = fmaf(xr[ci + 0], wreg[ci + 0], a0);
      a1 = fmaf(xr[ci + 1], wreg[ci + 1], a1);
      a2 = fmaf(xr[ci + 2], wreg[ci + 2], a2);
      a3 = fmaf(xr[ci + 3], wreg[ci + 3], a3);
    }
    up[(size_t)(n * 4 + j) * 64 + lane] = (a0 + a1) + (a2 + a3);
  }
}

// ---------------- pair-list LDS-tiled GEMM ----------------
// Block: 64 pairs x COUT cols, K=64. A^T staged in LDS (stride 68), W in LDS.
// Thread (mi=tid>>4, ci=tid&15) computes rows 4mi..4mi+3, cols CW*ci..
template <int COUT>
__global__ void __launch_bounds__(256) k_gemm2(const float* __restrict__ x,   // (NF+1) x 64, row NF zero
                                               const float* __restrict__ w,   // [27][64][COUT]
                                               const int* __restrict__ in_idx, int mmax, int NF,
                                               const int* __restrict__ cnt, const int* __restrict__ base,
                                               float* __restrict__ Cbuf) {
  constexpr int CW = COUT / 16;  // cols per thread: 4 (COUT=64) or 2 (COUT=32)
  constexpr int STA = 68;        // A^T row stride: 16B-aligned b128, conflict-free
  __shared__ float At[64 * STA];  // A^T[kk][m]
  __shared__ float Ws[64 * COUT]; // W[kk][c]
  __shared__ int sidx[64];

  const int k = blockIdx.y;
  const int ck = cnt[k];
  const int m0 = blockIdx.x * 64;
  if (m0 >= ck) return;
  const int tid = threadIdx.x;

  if (tid < 64) {
    int m = m0 + tid;
    sidx[tid] = (m < ck) ? in_idx[(size_t)k * mmax + m] : NF;  // pad -> zero row
  }
  {  // stage W panel (contiguous copy)
    const float4* wsrc = (const float4*)(w + (size_t)k * 64 * COUT);
    float4* wdst = (float4*)Ws;
#pragma unroll
    for (int p = 0; p < 64 * COUT / 4 / 256; ++p) wdst[tid + p * 256] = wsrc[tid + p * 256];
  }
  __syncthreads();
  {  // stage A^T: 4 passes; row=tid&15(+16/pass), 16B chunk=tid>>4
    const int r0 = tid & 15;
    const int cb = tid >> 4;  // floats 4cb..4cb+3
#pragma unroll
    for (int p = 0; p < 4; ++p) {
      int row = r0 + p * 16;
      float4 v = *(const float4*)(x + (size_t)sidx[row] * 64 + cb * 4);
      At[(cb * 4 + 0) * STA + row] = v.x;
      At[(cb * 4 + 1) * STA + row] = v.y;
      At[(cb * 4 + 2) * STA + row] = v.z;
      At[(cb * 4 + 3) * STA + row] = v.w;
    }
  }
  __syncthreads();

  const int mi = tid >> 4;  // 0..15
  const int ci = tid & 15;  // 0..15
  float acc[4][CW];
#pragma unroll
  for (int i = 0; i < 4; ++i)
#pragma unroll
    for (int j = 0; j < CW; ++j) acc[i][j] = 0.f;

#pragma unroll 4
  for (int kk = 0; kk < 64; ++kk) {
    float4 a = *(const float4*)(At + kk * STA + mi * 4);
    const float* brow = Ws + kk * COUT + ci * CW;
    float b[CW];
#pragma unroll
    for (int j = 0; j < CW; ++j) b[j] = brow[j];
    float av[4] = {a.x, a.y, a.z, a.w};
#pragma unroll
    for (int i = 0; i < 4; ++i)
#pragma unroll
      for (int j = 0; j < CW; ++j) acc[i][j] = fmaf(av[i], b[j], acc[i][j]);
  }

  const int bk = base[k];
#pragma unroll
  for (int i = 0; i < 4; ++i) {
    float* dst = Cbuf + (size_t)(bk + m0 + mi * 4 + i) * COUT + ci * CW;
#pragma unroll
    for (int j = 0; j < CW; ++j) dst[j] = acc[i][j];
  }
}

// ---------------- reduce partials + BN stats ----------------
template <int COUT>
__global__ void __launch_bounds__(256) k_red(const float* __restrict__ Cbuf, const int* __restrict__ pos,
                                             float* __restrict__ y, float* __restrict__ s1,
                                             float* __restrict__ s2, int NF) {
  constexpr int C4 = COUT / 4;
  const int c4 = threadIdx.x & (C4 - 1);
  const int rl = threadIdx.x / C4;
  const int rpb = 256 / C4;
  float4 p1 = make_float4(0, 0, 0, 0), p2 = make_float4(0, 0, 0, 0);
  for (int o = blockIdx.x * rpb + rl; o < NF; o += gridDim.x * rpb) {
    float4 acc = make_float4(0, 0, 0, 0);
#pragma unroll
    for (int k = 0; k < 27; ++k) {
      int p = pos[(size_t)k * NF + o];
      if (p >= 0) {
        float4 v = *(const float4*)(Cbuf + (size_t)p * COUT + c4 * 4);
        acc = f4add(acc, v);
      }
    }
    *(float4*)(y + (size_t)o * COUT + c4 * 4) = acc;
    p1 = f4add(p1, acc);
    p2 = f4add(p2, make_float4(acc.x * acc.x, acc.y * acc.y, acc.z * acc.z, acc.w * acc.w));
  }
  __shared__ float4 sh[256];
  sh[threadIdx.x] = p1;
  __syncthreads();
  if (rl == 0) {
    float4 t = make_float4(0, 0, 0, 0);
    for (int r = 0; r < rpb; ++r) t = f4add(t, sh[r * C4 + c4]);
    atomicAdd(s1 + c4 * 4 + 0, t.x); atomicAdd(s1 + c4 * 4 + 1, t.y);
    atomicAdd(s1 + c4 * 4 + 2, t.z); atomicAdd(s1 + c4 * 4 + 3, t.w);
  }
  __syncthreads();
  sh[threadIdx.x] = p2;
  __syncthreads();
  if (rl == 0) {
    float4 t = make_float4(0, 0, 0, 0);
    for (int r = 0; r < rpb; ++r) t = f4add(t, sh[r * C4 + c4]);
    atomicAdd(s2 + c4 * 4 + 0, t.x); atomicAdd(s2 + c4 * 4 + 1, t.y);
    atomicAdd(s2 + c4 * 4 + 2, t.z); atomicAdd(s2 + c4 * 4 + 3, t.w);
  }
}

// ---------------- xcat = [ELU(BN(y1)), max_t(skip)] ----------------
__global__ void __launch_bounds__(256) k_xcat(const float* __restrict__ y1, const float* __restrict__ skip,
                                              const float* __restrict__ gamma, const float* __restrict__ beta,
                                              const float* __restrict__ s1, const float* __restrict__ s2,
                                              float* __restrict__ xcat, int NF) {
  int t = blockIdx.x * blockDim.x + threadIdx.x;
  if (t >= NF * 32) return;
  int c = t & 31, o = t >> 5;
  float invn = 1.f / (float)NF;
  float m = s1[c] * invn;
  float var = s2[c] * invn - m * m;
  float sc = rsqrtf(var + 1e-5f) * gamma[c];
  float v = (y1[(size_t)o * 32 + c] - m) * sc + beta[c];
  xcat[(size_t)o * 64 + c] = elu(v);
  float a = skip[((size_t)o * 2) * 32 + c];
  float b = skip[((size_t)o * 2 + 1) * 32 + c];
  xcat[(size_t)o * 64 + 32 + c] = fmaxf(a, b);
}

// ---------------- h = ELU(BN(y)) ----------------
__global__ void __launch_bounds__(256) k_norm(const float* __restrict__ y, const float* __restrict__ gamma,
                                              const float* __restrict__ beta, const float* __restrict__ s1,
                                              const float* __restrict__ s2, float* __restrict__ h, int NF) {
  int t = blockIdx.x * blockDim.x + threadIdx.x;
  if (t >= NF * 64) return;
  int c = t & 63;
  float invn = 1.f / (float)NF;
  float m = s1[c] * invn;
  float var = s2[c] * invn - m * m;
  float sc = rsqrtf(var + 1e-5f) * gamma[c];
  h[t] = elu((y[t] - m) * sc + beta[c]);
}

// ---------------- out = ELU(ELU(BN(y3)) + xcat) ----------------
__global__ void __launch_bounds__(256) k_final(const float* __restrict__ y, const float* __restrict__ gamma,
                                               const float* __restrict__ beta, const float* __restrict__ s1,
                                               const float* __restrict__ s2, const float* __restrict__ xcat,
                                               float* __restrict__ out, int NF) {
  int t = blockIdx.x * blockDim.x + threadIdx.x;
  if (t >= NF * 64) return;
  int c = t & 63;
  float invn = 1.f / (float)NF;
  float m = s1[c] * invn;
  float var = s2[c] * invn - m * m;
  float sc = rsqrtf(var + 1e-5f) * gamma[c];
  float v = elu((y[t] - m) * sc + beta[c]);
  out[t] = elu(v + xcat[t]);
}

extern "C" void kernel_launch(void* const* d_in, const int* in_sizes, int n_in,
                              void* d_out, int out_size, void* d_ws, size_t ws_size,
                              hipStream_t stream) {
  const float* x_feats  = (const float*)d_in[0];
  const float* skip     = (const float*)d_in[1];
  const float* w_up     = (const float*)d_in[2];
  const float* w_upconv = (const float*)d_in[3];
  const float* bn1_g    = (const float*)d_in[4];
  const float* bn1_b    = (const float*)d_in[5];
  const float* convs_w  = (const float*)d_in[6];
  const float* convs_g  = (const float*)d_in[7];
  const float* convs_b  = (const float*)d_in[8];
  const int*   in_idx   = (const int*)d_in[9];
  const int*   out_idx  = (const int*)d_in[10];

  const int NC = in_sizes[0] / 64;
  const int NF = 4 * NC;
  const int mmax = in_sizes[9] / 27;

  char* ws = (char*)d_ws;
  size_t off = 0;
  auto alloc = [&](size_t bytes) -> void* {
    void* p = ws + off;
    off += (bytes + 255) & ~(size_t)255;
    return p;
  };
  int*   pos   = (int*)alloc((size_t)27 * NF * 4);
  int*   cnt   = (int*)alloc(32 * 4);
  int*   basep = (int*)alloc(32 * 4);
  float* stats = (float*)alloc(384 * 4);  // 3 stages x (sum, sumsq) x 64
  float* up    = (float*)alloc(((size_t)NF + 1) * 64 * 4);
  float* xcat  = (float*)alloc(((size_t)NF + 1) * 64 * 4);
  float* y     = (float*)alloc((size_t)NF * 64 * 4);  // reused y1/y2/y3
  float* Cb    = (float*)(ws + off);                  // remainder: partial rows
  float* h     = up;  // up is dead after the first k_gemm2; pad row stays zero

  k_init<<<1024, 256, 0, stream>>>(pos, stats, up + (size_t)NF * 64,
                                   xcat + (size_t)NF * 64, 27 * NF);
  k_meta<<<1, 64, 0, stream>>>(in_idx, mmax, NF, cnt, basep);
  dim3 gs((mmax + 255) / 256, 27);
  k_scatter<<<gs, 256, 0, stream>>>(out_idx, mmax, NF, cnt, basep, pos);
  k_up<16><<<(NC + 15) / 16, 256, 0, stream>>>(x_feats, w_up, up, NC);

  dim3 gg((mmax + 63) / 64, 27);  // 64-pair tiles; blocks past cnt[k] exit
  // upconv (COUT=32) -> BN1 stats
  k_gemm2<32><<<gg, 256, 0, stream>>>(up, w_upconv, in_idx, mmax, NF, cnt, basep, Cb);
  k_red<32><<<320, 256, 0, stream>>>(Cb, pos, y, stats + 0, stats + 64, NF);
  k_xcat<<<(NF * 32 + 255) / 256, 256, 0, stream>>>(y, skip, bn1_g, bn1_b,
                                                    stats + 0, stats + 64, xcat, NF);
  // conv1
  k_gemm2<64><<<gg, 256, 0, stream>>>(xcat, convs_w, in_idx, mmax, NF, cnt, basep, Cb);
  k_red<64><<<640, 256, 0, stream>>>(Cb, pos, y, stats + 128, stats + 192, NF);
  k_norm<<<(NF * 64 + 255) / 256, 256, 0, stream>>>(y, convs_g, convs_b,
                                                    stats + 128, stats + 192, h, NF);
  // conv2
  k_gemm2<64><<<gg, 256, 0, stream>>>(h, convs_w + 27 * 64 * 64, in_idx, mmax, NF, cnt, basep, Cb);
  k_red<64><<<640, 256, 0, stream>>>(Cb, pos, y, stats + 256, stats + 320, NF);
  k_final<<<(NF * 64 + 255) / 256, 256, 0, stream>>>(y, convs_g + 64, convs_b + 64,
                                                     stats + 256, stats + 320, xcat,
                                                     (float*)d_out, NF);
}